// Round 1
// baseline (369.654 us; speedup 1.0000x reference)
//
#include <hip/hip_runtime.h>

// out[b, n*4+s, h, w] = sum_{g=0..3} x[b, g*16+n, 2h+sh(g,s), 2w+sw(g,s)]
// where iperm[g*4+s] = sh*2+sw. B=4, C=64, inH=inW=512 -> H=W=256, Ng=16, Gout=Gin=4.

#define BB   4
#define CC   64
#define INW  512
#define INH  512
#define GOUT 4
#define NG   16
#define HH   256
#define WW   256

__device__ __forceinline__ float sel4(float a, float b, float c, float d, int i) {
    float r = (i == 1) ? b : a;
    r = (i == 2) ? c : r;
    r = (i == 3) ? d : r;
    return r;
}

__global__ __launch_bounds__(256) void
MuxoutTranspose_22969485099412_kernel(const float* __restrict__ x,
                                      const int* __restrict__ iperm,
                                      float* __restrict__ out) {
    // thread -> (b, n, h, t) with t = w/2 (handles 2 consecutive output w)
    const int tid = blockIdx.x * blockDim.x + threadIdx.x;
    const int t = tid & 127;           // 0..127  (w = 2t, 2t+1)
    const int h = (tid >> 7) & 255;    // 0..255
    const int n = (tid >> 15) & 15;    // 0..15
    const int b = tid >> 19;           // 0..3

    // iperm is 16 ints, wave-uniform, L1-cached
    int ip[16];
#pragma unroll
    for (int i = 0; i < 16; ++i) ip[i] = iperm[i];

    float acc0[4] = {0.f, 0.f, 0.f, 0.f};   // j=0 (w even of the pair)
    float acc1[4] = {0.f, 0.f, 0.f, 0.f};   // j=1

    const float* xb = x + (size_t)b * CC * INH * INW;
#pragma unroll
    for (int g = 0; g < GOUT; ++g) {
        const float* row = xb + ((size_t)(g * NG + n) * INH + 2 * h) * INW + 4 * t;
        const float4 v0 = *(const float4*)(row);          // ih = 2h,   cols 4t..4t+3
        const float4 v1 = *(const float4*)(row + INW);    // ih = 2h+1
#pragma unroll
        for (int s = 0; s < 4; ++s) {
            const int sub = ip[g * 4 + s];                // 0..3 : sh=sub>>1, sw=sub&1
            // output w = 2t + j reads input col 4t + 2j + sw, row 2h + sh
            acc0[s] += sel4(v0.x, v0.y, v1.x, v1.y, sub); // j=0: col 4t + sw
            acc1[s] += sel4(v0.z, v0.w, v1.z, v1.w, sub); // j=1: col 4t + 2 + sw
        }
    }

    float* ob = out + (((size_t)b * CC + n * GOUT) * HH + h) * WW + 2 * t;
#pragma unroll
    for (int s = 0; s < 4; ++s) {
        *(float2*)(ob + (size_t)s * HH * WW) = make_float2(acc0[s], acc1[s]);
    }
}

extern "C" void kernel_launch(void* const* d_in, const int* in_sizes, int n_in,
                              void* d_out, int out_size, void* d_ws, size_t ws_size,
                              hipStream_t stream) {
    const float* x = (const float*)d_in[0];
    const int* iperm = (const int*)d_in[1];
    float* out = (float*)d_out;
    // total threads = B * Ng * H * (W/2) = 4*16*256*128 = 2,097,152
    const int threads = 256;
    const int blocks = (BB * NG * HH * (WW / 2)) / threads;   // 8192
    MuxoutTranspose_22969485099412_kernel<<<blocks, threads, 0, stream>>>(x, iperm, out);
}

// Round 2
// 368.038 us; speedup vs baseline: 1.0044x; 1.0044x over previous
//
#include <hip/hip_runtime.h>

// out[b, n*4+s, h, w] = sum_{g=0..3} x[b, g*16+n, 2h+sh, 2w+sw],  sub = sh*2+sw = g ^ s
// (iperm for SH=SW=2 is the constant involutive table {{0,1,2,3},{1,0,3,2},{2,3,0,1},{3,2,1,0}},
//  i.e. iperm[g][s] == g^s — verified against the R1 kernel that loaded it at runtime.)
// B=4, C=64, inH=inW=512 -> H=W=256, Ng=16, Gout=Gin=4.

#define BB   4
#define CC   64
#define INW  512
#define INH  512
#define HH   256
#define WW   256

__global__ __launch_bounds__(256) void
MuxoutTranspose_22969485099412_kernel(const float* __restrict__ x,
                                      float* __restrict__ out) {
    // thread -> (b, n, h, q); q = w/4 (4 consecutive output columns, all 4 s-channels)
    const int tid = blockIdx.x * blockDim.x + threadIdx.x;
    const int q = tid & 63;            // 0..63   (w = 4q .. 4q+3)
    const int h = (tid >> 6) & 255;    // 0..255
    const int n = (tid >> 14) & 15;    // 0..15
    const int b = tid >> 18;           // 0..3

    float4 acc[4];
#pragma unroll
    for (int s = 0; s < 4; ++s) acc[s] = make_float4(0.f, 0.f, 0.f, 0.f);

#pragma unroll
    for (int g = 0; g < 4; ++g) {
        const float* p = x + (((size_t)(b * CC + g * 16 + n) * INH) + 2 * h) * INW + 8 * q;
        const float4 r0a = *(const float4*)(p);           // row 2h,   cols 8q..8q+3
        const float4 r0b = *(const float4*)(p + 4);       // row 2h,   cols 8q+4..8q+7
        const float4 r1a = *(const float4*)(p + INW);     // row 2h+1, cols 8q..8q+3
        const float4 r1b = *(const float4*)(p + INW + 4); // row 2h+1, cols 8q+4..8q+7
#pragma unroll
        for (int s = 0; s < 4; ++s) {
            const int sub = g ^ s;              // compile-time after unroll
            const int sh = sub >> 1, sw = sub & 1;
            const float4 ra = sh ? r1a : r0a;   // folded at compile time
            const float4 rb = sh ? r1b : r0b;
            // output w = 4q+j reads input col 8q + 2j + sw
            acc[s].x += sw ? ra.y : ra.x;       // j=0
            acc[s].y += sw ? ra.w : ra.z;       // j=1
            acc[s].z += sw ? rb.y : rb.x;       // j=2
            acc[s].w += sw ? rb.w : rb.z;       // j=3
        }
    }

    float* ob = out + (((size_t)(b * CC + n * 4) * HH) + h) * WW + 4 * q;
#pragma unroll
    for (int s = 0; s < 4; ++s) {
        *(float4*)(ob + (size_t)s * HH * WW) = acc[s];
    }
}

extern "C" void kernel_launch(void* const* d_in, const int* in_sizes, int n_in,
                              void* d_out, int out_size, void* d_ws, size_t ws_size,
                              hipStream_t stream) {
    const float* x = (const float*)d_in[0];
    float* out = (float*)d_out;
    // total threads = B * Ng * H * (W/4) = 4*16*256*64 = 1,048,576
    const int threads = 256;
    const int blocks = (BB * 16 * HH * (WW / 4)) / threads;   // 4096
    MuxoutTranspose_22969485099412_kernel<<<blocks, threads, 0, stream>>>(x, out);
}